// Round 28
// baseline (360.540 us; speedup 1.0000x reference)
//
#include <hip/hip_runtime.h>
#include <cstdint>
#include <cstddef>

using u16 = unsigned short;
using u32 = unsigned int;
typedef __attribute__((ext_vector_type(8))) short bf16x8;
typedef __attribute__((ext_vector_type(4))) float f32x4;

static constexpr int NUM_PEAK = 28000;
static constexpr int NUM_GENE = 12000;
static constexpr int N_NODES  = NUM_PEAK + NUM_GENE;   // 40000
static constexpr int N_EDGES  = 640000;
static constexpr int E_TOTAL  = N_EDGES + N_NODES;     // 680000
static constexpr int NT       = 100;
static constexpr int NT2      = 200;
static constexpr int NTP      = 128;
static constexpr int TH       = 512;
static constexpr int EMB      = 64;
static constexpr int HID      = 128;
static constexpr int BATCH    = 256;
static constexpr int SCAN_CHUNK = 1024;
static constexpr int SCAN_NB  = (N_NODES + SCAN_CHUNK - 1) / SCAN_CHUNK;  // 40
static constexpr int ENC_CH   = 1280;                  // enc1 k-chunk (20 x 64)
static constexpr int KPG      = 12032;
static constexpr int KPP      = 28032;
static constexpr int KSPG     = (NUM_GENE + ENC_CH - 1) / ENC_CH;  // 10
static constexpr int KSPP     = (NUM_PEAK + ENC_CH - 1) / ENC_CH;  // 22
static constexpr int ENC1B    = 8 * 4 * (KSPG + KSPP);             // 1024
static constexpr int DEGB     = (E_TOTAL + 255) / 256;             // 2657
static constexpr int PADGB    = BATCH * KPG / 8 / 256;             // 1504
static constexpr int PADPB    = BATCH * KPP / 8 / 256;             // 3504
static constexpr int CS_ROWS  = 128;
static constexpr int NBMAX    = (NUM_PEAK + CS_ROWS - 1) / CS_ROWS;  // 219
#define BN_EPS 1e-5f

__device__ __forceinline__ u16 f2bf(float f) {
  u32 b = __float_as_uint(f);
  return (u16)((b + 0x7FFFu + ((b >> 16) & 1u)) >> 16);
}

// ---------------------------------------------------------------------------
struct CvtJobs {
  const float* src[12];
  u16* dst[12];
  u32 n[12];
  u32 start[12];
  int count;
};

__device__ void dev_cvt_all(const CvtJobs& J, int bid) {
  int seg = 0;
  while (seg + 1 < J.count && bid >= (int)J.start[seg + 1]) ++seg;
  const float* __restrict__ src = J.src[seg];
  u16* __restrict__ dst = J.dst[seg];
  const u32 n = J.n[seg];
  const u32 i = (u32)(bid - J.start[seg]) * 2048u + threadIdx.x * 8u;
  if (i + 8 <= n) {
    float4 a = *(const float4*)(src + i);
    float4 b = *(const float4*)(src + i + 4);
    ushort4 o0{f2bf(a.x), f2bf(a.y), f2bf(a.z), f2bf(a.w)};
    ushort4 o1{f2bf(b.x), f2bf(b.y), f2bf(b.z), f2bf(b.w)};
    *(ushort4*)(dst + i) = o0;
    *(ushort4*)(dst + i + 4) = o1;
  } else {
    for (u32 j = i; j < n; ++j) dst[j] = f2bf(src[j]);
  }
}

__device__ void dev_cvt_pad(const float* __restrict__ src, u16* __restrict__ dst,
                            int K, int Kp, int bid) {
  const size_t i = ((size_t)bid * 256 + threadIdx.x) * 8;   // always < BATCH*Kp
  const int col = (int)(i % Kp);
  const size_t row = i / Kp;
  ushort4 o0{0, 0, 0, 0}, o1{0, 0, 0, 0};
  if (col + 8 <= K) {
    const float* s = src + row * K + col;
    float4 a = *(const float4*)s;
    float4 b = *(const float4*)(s + 4);
    o0 = ushort4{f2bf(a.x), f2bf(a.y), f2bf(a.z), f2bf(a.w)};
    o1 = ushort4{f2bf(b.x), f2bf(b.y), f2bf(b.z), f2bf(b.w)};
  }
  *(ushort4*)(dst + i) = o0;
  *(ushort4*)(dst + i + 4) = o1;
}

// deg_count also records each edge's slot within its destination's bucket,
// so the later scatter needs NO atomic.
__device__ void dev_deg_count(const int* __restrict__ ei, int* __restrict__ deg,
                              int* __restrict__ pos, int bid) {
  const int e = bid * 256 + threadIdx.x;
  if (e >= E_TOTAL) return;
  const int d = (e < N_EDGES) ? ei[N_EDGES + e] : e - N_EDGES;
  pos[e] = atomicAdd(&deg[d], 1);
}

__device__ void dev_csr_scatter(const int* __restrict__ ei,
                                const int* __restrict__ row_ptr,
                                const int* __restrict__ pos,
                                int* __restrict__ csr_src, int bid) {
  const int e = bid * 256 + threadIdx.x;
  if (e >= E_TOTAL) return;
  int s, d;
  if (e < N_EDGES) { s = ei[e]; d = ei[N_EDGES + e]; }
  else { s = d = e - N_EDGES; }
  csr_src[row_ptr[d] + pos[e]] = s;      // atomic-free
}

// megaA: deg_count || cvt_pad(gene) || cvt_pad(peak) || cvt_all
__global__ __launch_bounds__(256) void megaA(
    const int* ei, int* deg, int* pos,
    const float* GeneN, u16* GeneNb, const float* PeakN, u16* PeakNb,
    CvtJobs J) {
  const int bid = blockIdx.x;
  if (bid < DEGB) dev_deg_count(ei, deg, pos, bid);
  else if (bid < DEGB + PADGB) dev_cvt_pad(GeneN, GeneNb, NUM_GENE, KPG, bid - DEGB);
  else if (bid < DEGB + PADGB + PADPB) dev_cvt_pad(PeakN, PeakNb, NUM_PEAK, KPP, bid - DEGB - PADGB);
  else dev_cvt_all(J, bid - DEGB - PADGB - PADPB);
}

// ---------------------------------------------------------------------------
// Single-launch scan with counter barrier (40 blocks, all co-resident).
// ---------------------------------------------------------------------------
__global__ __launch_bounds__(256) void scan_fused(
    const int* __restrict__ deg, int* __restrict__ bsum,
    int* __restrict__ row_ptr, int* __restrict__ cnt) {
  const int t = threadIdx.x;
  const int b = blockIdx.x;
  const int base = b * SCAN_CHUNK + t * 4;
  int v[4], s = 0;
#pragma unroll
  for (int i = 0; i < 4; ++i) {
    const int idx = base + i;
    v[i] = (idx < N_NODES) ? deg[idx] : 0;
    s += v[i];
  }
  const int lane = t & 63, w = t >> 6;
  int x = s;
  for (int o = 1; o < 64; o <<= 1) {
    int y = __shfl_up(x, o);
    if (lane >= o) x += y;
  }
  __shared__ int wtot[4];
  if (lane == 63) wtot[w] = x;
  __syncthreads();
  int woff = 0;
  for (int i = 0; i < w; ++i) woff += wtot[i];
  const int btotal = wtot[0] + wtot[1] + wtot[2] + wtot[3];
  if (t == 0) {
    bsum[b] = btotal;
    __threadfence();
    atomicAdd(cnt, 1);
    while (atomicAdd(cnt, 0) < SCAN_NB) ;
  }
  __syncthreads();
  int bexcl = 0;
  for (int i = 0; i < b; ++i) bexcl += atomicAdd(&bsum[i], 0);
  int excl = bexcl + woff + x - s;
#pragma unroll
  for (int i = 0; i < 4; ++i) {
    const int idx = base + i;
    if (idx < N_NODES) { row_ptr[idx] = excl; excl += v[i]; }
  }
  if (b == 0 && t == 0) row_ptr[N_NODES] = E_TOTAL;
}

// ---------------------------------------------------------------------------
// Device GEMM (dual-use): C(M,N)=A@B^T, 64x64 tile, 4 waves, BK=32.
// ---------------------------------------------------------------------------
struct GP {
  const u16* A; const u16* B; float* C; u16* Cb; const float* bias;
  int M, N, K;
};

__device__ void dev_gemm_bt(const GP g, int bxx, int byy, char* smem) {
  u16 (*As)[40] = (u16(*)[40])smem;
  u16 (*Bs)[40] = (u16(*)[40])(smem + 64 * 40 * 2);
  const int M = g.M, N = g.N, K = g.K;
  const int tid = threadIdx.x;
  const int bm = byy * 64, bn = bxx * 64;
  if (bm >= M || bn >= N) return;
  const int w = tid >> 6, lane = tid & 63;
  const int wm = (w >> 1) * 32, wn = (w & 1) * 32;
  const int fr = lane & 15;
  const int ks = (lane >> 4) * 8;
  const int srow = tid >> 2, sseg = (tid & 3) * 8;
  f32x4 acc[2][2] = {};
  for (int kt = 0; kt < K; kt += 32) {
    const int gk = kt + sseg;
    {
      const int gm = bm + srow;
      bf16x8 v = {0, 0, 0, 0, 0, 0, 0, 0};
      if (gm < M) v = *(const bf16x8*)(g.A + (size_t)gm * K + gk);
      *(bf16x8*)&As[srow][sseg] = v;
    }
    {
      const int gn = bn + srow;
      bf16x8 v = {0, 0, 0, 0, 0, 0, 0, 0};
      if (gn < N) v = *(const bf16x8*)(g.B + (size_t)gn * K + gk);
      *(bf16x8*)&Bs[srow][sseg] = v;
    }
    __syncthreads();
    bf16x8 a0 = *(const bf16x8*)&As[wm + fr][ks];
    bf16x8 a1 = *(const bf16x8*)&As[wm + 16 + fr][ks];
    bf16x8 b0 = *(const bf16x8*)&Bs[wn + fr][ks];
    bf16x8 b1 = *(const bf16x8*)&Bs[wn + 16 + fr][ks];
    acc[0][0] = __builtin_amdgcn_mfma_f32_16x16x32_bf16(a0, b0, acc[0][0], 0, 0, 0);
    acc[0][1] = __builtin_amdgcn_mfma_f32_16x16x32_bf16(a0, b1, acc[0][1], 0, 0, 0);
    acc[1][0] = __builtin_amdgcn_mfma_f32_16x16x32_bf16(a1, b0, acc[1][0], 0, 0, 0);
    acc[1][1] = __builtin_amdgcn_mfma_f32_16x16x32_bf16(a1, b1, acc[1][1], 0, 0, 0);
    __syncthreads();
  }
#pragma unroll
  for (int fi = 0; fi < 2; ++fi)
#pragma unroll
    for (int fj = 0; fj < 2; ++fj)
#pragma unroll
      for (int r = 0; r < 4; ++r) {
        const int row = bm + wm + fi * 16 + (lane >> 4) * 4 + r;
        const int col = bn + wn + fj * 16 + fr;
        if (row < M && col < N) {
          const float v = acc[fi][fj][r];
          if (g.Cb) g.Cb[(size_t)row * N + col] = f2bf(v + (g.bias ? g.bias[col] : 0.f));
          else g.C[(size_t)row * N + col] = v + (g.bias ? g.bias[col] : 0.f);
        }
      }
}

// ---------------------------------------------------------------------------
// Device encoder-L1 GEMM (v9): 64x64 tile, stores fp32 partial slices.
// ---------------------------------------------------------------------------
__device__ __forceinline__ int swz64(int row, int colu16) {
  return row * 64 + ((((colu16 >> 3) ^ row) & 7) << 3) + (colu16 & 7);
}

__device__ void dev_enc1(
    const u16* __restrict__ A0, const float* __restrict__ B0, float* __restrict__ P0,
    const u16* __restrict__ A1, const float* __restrict__ B1, float* __restrict__ P1,
    int bid, char* smem) {
  const int cpx = ENC1B >> 3;
  const int f2 = (bid & 7) * cpx + (bid >> 3);
  const int bx = f2 % 8;
  const int by = (f2 / 8) % 4;
  const int bz = f2 / 32;
  const bool second = (bz >= KSPG);
  const u16* __restrict__ A = second ? A1 : A0;
  const float* __restrict__ B = second ? B1 : B0;
  float* __restrict__ P = second ? P1 : P0;
  const int K = second ? NUM_PEAK : NUM_GENE;
  const int Kp = second ? KPP : KPG;
  const int zz = second ? bz - KSPG : bz;
  const int k0 = zz * ENC_CH;
  const int k1 = min(K, k0 + ENC_CH);
  u16* As = (u16*)smem;
  u16* Bs = (u16*)(smem + 8192);
  const int tid = threadIdx.x;
  const int bm = by * 64;
  const int bn = bx * 64;
  const int w = tid >> 6, lane = tid & 63;
  const int wm = w * 16;
  const int fr = lane & 15, g = lane >> 4;
  const int ar = tid >> 2, acol = (tid & 3) * 16;
  const int br = tid >> 2, bcol = (tid & 3) * 16;
  const u16* Abase = A + (size_t)(bm + ar) * Kp + acol;
  const float* Bbase = B + (size_t)(bn + br) * K + bcol;

  bf16x8 rA0, rA1;
  float4 rB0, rB1, rB2, rB3;
  auto LD = [&](int kt) {
    const u16* sa = Abase + kt;
    rA0 = *(const bf16x8*)(sa);
    rA1 = *(const bf16x8*)(sa + 8);
    if (kt + bcol + 16 <= K) {
      const float* sb = Bbase + kt;
      rB0 = *(const float4*)(sb);
      rB1 = *(const float4*)(sb + 4);
      rB2 = *(const float4*)(sb + 8);
      rB3 = *(const float4*)(sb + 12);
    } else {
      rB0 = float4{0.f, 0.f, 0.f, 0.f}; rB1 = rB0; rB2 = rB0; rB3 = rB0;
    }
  };
  auto ST = [&]() {
    *(bf16x8*)&As[swz64(ar, acol)] = rA0;
    *(bf16x8*)&As[swz64(ar, acol + 8)] = rA1;
    ushort4 p0{f2bf(rB0.x), f2bf(rB0.y), f2bf(rB0.z), f2bf(rB0.w)};
    ushort4 p1{f2bf(rB1.x), f2bf(rB1.y), f2bf(rB1.z), f2bf(rB1.w)};
    ushort4 p2{f2bf(rB2.x), f2bf(rB2.y), f2bf(rB2.z), f2bf(rB2.w)};
    ushort4 p3{f2bf(rB3.x), f2bf(rB3.y), f2bf(rB3.z), f2bf(rB3.w)};
    const int b0 = swz64(br, bcol);
    const int b1 = swz64(br, bcol + 8);
    *(ushort4*)&Bs[b0] = p0;
    *(ushort4*)&Bs[b0 + 4] = p1;
    *(ushort4*)&Bs[b1] = p2;
    *(ushort4*)&Bs[b1 + 4] = p3;
  };

  f32x4 acc[4] = {};
  LD(k0);
  ST();
  for (int kt = k0; kt < k1; kt += 64) {
    __syncthreads();
    const bool more = (kt + 64 < k1);
    if (more) LD(kt + 64);
#pragma unroll
    for (int s = 0; s < 2; ++s) {
      const int kc = s * 32 + g * 8;
      bf16x8 a = *(const bf16x8*)&As[swz64(wm + fr, kc)];
#pragma unroll
      for (int fj = 0; fj < 4; ++fj) {
        bf16x8 b = *(const bf16x8*)&Bs[swz64(fj * 16 + fr, kc)];
        acc[fj] = __builtin_amdgcn_mfma_f32_16x16x32_bf16(a, b, acc[fj], 0, 0, 0);
      }
    }
    __syncthreads();
    if (more) ST();
  }
  float* Pz = P + (size_t)zz * TH * 256;
  const int row = bm + wm + g * 4;
#pragma unroll
  for (int fj = 0; fj < 4; ++fj) {
    const int col = bn + fj * 16 + fr;
    *(f32x4*)&Pz[(size_t)col * 256 + row] = acc[fj];
  }
}

// ---------------------------------------------------------------------------
template <int C>
__device__ void dev_gat(
    const u16* __restrict__ xl, const u16* __restrict__ xr,
    const float* __restrict__ att, const float* __restrict__ bias,
    const int* __restrict__ row_ptr, const int* __restrict__ csr_src,
    u16* __restrict__ out_b, int blk) {
  constexpr int CPL = C / 8;
  constexpr int W = CPL / 2;
  const int lane = threadIdx.x & 63;
  const int g = lane >> 3, li = lane & 7;
  const int d = blk * 4 + ((int)threadIdx.x >> 6);
  if (d >= N_NODES) return;
  const int c0 = li * CPL;
  float xrv[CPL], attv[CPL], acc[CPL];
  {
    const u32* xrw = (const u32*)(xr + (size_t)d * C + c0);
#pragma unroll
    for (int i = 0; i < W; ++i) {
      const u32 wv = xrw[i];
      xrv[2 * i]     = __uint_as_float(wv << 16);
      xrv[2 * i + 1] = __uint_as_float(wv & 0xffff0000u);
    }
  }
#pragma unroll
  for (int i = 0; i < CPL; ++i) { attv[i] = att[c0 + i]; acc[i] = 0.f; }
  float m = -INFINITY, den = 0.f;
  const int end = row_ptr[d + 1];
  int p = row_ptr[d] + g;
  int s = (p < end) ? csr_src[p] : 0;
  u32 w[W];
  {
    const u32* sw = (const u32*)(xl + (size_t)s * C + c0);
#pragma unroll
    for (int i = 0; i < W; ++i) w[i] = sw[i];
  }
  while (p < end) {
    const int sn = (p + 8 < end) ? csr_src[p + 8] : 0;
    u32 wn[W];
    {
      const u32* sw = (const u32*)(xl + (size_t)sn * C + c0);
#pragma unroll
      for (int i = 0; i < W; ++i) wn[i] = sw[i];
    }
    float xlv[CPL];
#pragma unroll
    for (int i = 0; i < W; ++i) {
      xlv[2 * i]     = __uint_as_float(w[i] << 16);
      xlv[2 * i + 1] = __uint_as_float(w[i] & 0xffff0000u);
    }
    float part = 0.f;
#pragma unroll
    for (int i = 0; i < CPL; ++i) {
      float x = xlv[i] + xrv[i];
      x = (x > 0.f) ? x : 0.2f * x;
      part += x * attv[i];
    }
    part += __shfl_xor(part, 1);
    part += __shfl_xor(part, 2);
    part += __shfl_xor(part, 4);
    const float nm = fmaxf(m, part);
    const float scale = __expf(m - nm);
    const float ex = __expf(part - nm);
    den = den * scale + ex;
#pragma unroll
    for (int i = 0; i < CPL; ++i) acc[i] = acc[i] * scale + ex * xlv[i];
    m = nm;
    p += 8;
#pragma unroll
    for (int i = 0; i < W; ++i) w[i] = wn[i];
  }
  float M = m;
  M = fmaxf(M, __shfl_xor(M, 8));
  M = fmaxf(M, __shfl_xor(M, 16));
  M = fmaxf(M, __shfl_xor(M, 32));
  const float gs = __expf(m - M);
  den *= gs;
  den += __shfl_xor(den, 8);
  den += __shfl_xor(den, 16);
  den += __shfl_xor(den, 32);
  const float inv = 1.f / (den + 1e-16f);
  float va[CPL];
#pragma unroll
  for (int i = 0; i < CPL; ++i) {
    float a = acc[i] * gs;
    a += __shfl_xor(a, 8);
    a += __shfl_xor(a, 16);
    a += __shfl_xor(a, 32);
    va[i] = a;
  }
  if (g == 0) {
    u32* dst = (u32*)(out_b + (size_t)d * C + c0);
#pragma unroll
    for (int i = 0; i < W; ++i) {
      const u16 lo = f2bf(fmaxf(va[2 * i] * inv + bias[c0 + 2 * i], 0.f));
      const u16 hi = f2bf(fmaxf(va[2 * i + 1] * inv + bias[c0 + 2 * i + 1], 0.f));
      dst[i] = (u32)lo | ((u32)hi << 16);
    }
  }
}

__device__ void dev_bn_body(float v, const float* gma, const float* be, int c,
                            u16* ob, float* red) {
  const int r = threadIdx.x;
  red[r] = v; __syncthreads();
  for (int s = BATCH / 2; s > 0; s >>= 1) { if (r < s) red[r] += red[r + s]; __syncthreads(); }
  const float mean = red[0] * (1.f / BATCH);
  __syncthreads();
  const float d = v - mean;
  red[r] = d * d; __syncthreads();
  for (int s = BATCH / 2; s > 0; s >>= 1) { if (r < s) red[r] += red[r + s]; __syncthreads(); }
  const float var = red[0] * (1.f / BATCH);
  ob[(size_t)r * TH + c] = f2bf(d * rsqrtf(var + BN_EPS) * gma[c] + be[c]);
}

__device__ void dev_bn_part(
    int cg, const float* __restrict__ PG, int nzG, const float* bg,
    const float* gg, const float* beg, u16* og,
    const float* __restrict__ PP, int nzP, const float* bp,
    const float* gp, const float* bep, u16* op, float* red) {
  int c = cg;
  const float *P, *b, *gma, *be; u16* ob; int nz;
  if (c < TH) { P = PG; nz = nzG; b = bg; gma = gg; be = beg; ob = og; }
  else { c -= TH; P = PP; nz = nzP; b = bp; gma = gp; be = bep; ob = op; }
  const int r = threadIdx.x;
  float v = 0.f;
  const float* base = P + (size_t)c * 256 + r;
  for (int z = 0; z < nz; ++z) v += base[(size_t)z * TH * 256];
  v = fmaxf(v + b[c], 0.f);
  dev_bn_body(v, gma, be, c, ob, red);
}

__device__ void dev_bn2(
    int cg, const float* __restrict__ Hg, const float* bg,
    const float* gg, const float* beg, u16* og,
    const float* __restrict__ Hp, const float* bp,
    const float* gp, const float* bep, u16* op, float* red) {
  int c = cg;
  const float *H, *b, *gma, *be; u16* ob;
  if (c < TH) { H = Hg; b = bg; gma = gg; be = beg; ob = og; }
  else { c -= TH; H = Hp; b = bp; gma = gp; be = bep; ob = op; }
  const int r = threadIdx.x;
  float v = fmaxf(H[(size_t)r * TH + c] + b[c], 0.f);
  dev_bn_body(v, gma, be, c, ob, red);
}

__device__ void dev_row_kl(
    int b, int which, const float* __restrict__ mld, const float* __restrict__ mlj,
    const float* mu_b, const float* ls_b,
    u16* thd, u16* thj, float* kl_out, float* red) {
  const float* ml = which ? mlj : mld;
  u16* thb = which ? thj : thd;
  const int t = threadIdx.x;
  const bool act = (t < NT);
  float mu = 0.f, ls = 0.f, term = 0.f;
  if (act) {
    mu = ml[(size_t)b * NT2 + t] + mu_b[t];
    ls = 2.f * (ml[(size_t)b * NT2 + NT + t] + ls_b[t]);
    term = 1.f + ls - mu * mu - expf(ls);
  }
  red[t] = act ? term : 0.f; __syncthreads();
  for (int s = 64; s > 0; s >>= 1) { if (t < s) red[t] += red[t + s]; __syncthreads(); }
  if (t == 0) atomicAdd(kl_out, -0.5f * red[0] * (1.f / BATCH));
  __syncthreads();
  red[t] = act ? mu : -INFINITY; __syncthreads();
  for (int s = 64; s > 0; s >>= 1) { if (t < s) red[t] = fmaxf(red[t], red[t + s]); __syncthreads(); }
  const float mx = red[0];
  __syncthreads();
  const float e = act ? expf(mu - mx) : 0.f;
  red[t] = e; __syncthreads();
  for (int s = 64; s > 0; s >>= 1) { if (t < s) red[t] += red[t + s]; __syncthreads(); }
  thb[(size_t)b * NTP + t] = act ? f2bf(e / red[0]) : (u16)0;
}

// Guarded-body version (no early return) so callers may sync/count after.
__device__ void dev_col_stats(
    int bx, int sec, const float* __restrict__ Lg, const float* __restrict__ Lp,
    float* __restrict__ bstats) {
  const float* L = sec ? Lp : Lg;
  const int M = sec ? NUM_PEAK : NUM_GENE;
  const int r0 = bx * CS_ROWS;
  const int c = threadIdx.x;
  if (c < NT && r0 < M) {
    const int rend = min(r0 + CS_ROWS, M);
    float m = -INFINITY, s = 0.f;
    for (int r = r0; r < rend; ++r) {
      const float v = L[(size_t)r * NT + c];
      const float nm = fmaxf(m, v);
      s = s * __expf(m - nm) + __expf(v - nm);
      m = nm;
    }
    float* bs = bstats + (((size_t)sec * NT + c) * NBMAX + bx) * 2;
    bs[0] = m;
    bs[1] = s;
  }
}

// Wave-parallel per-column merge (threads < 64 participate).
__device__ void dev_col_merge(
    int c, int sec, const float* __restrict__ bstats, int nbG, int nbP,
    float* __restrict__ mstat, float* __restrict__ istat) {
  const int nb = sec ? nbP : nbG;
  const int l = threadIdx.x;           // < 64
  const float* bs = bstats + ((size_t)sec * NT + c) * NBMAX * 2;
  float m = -INFINITY, s = 0.f;
  for (int b = l; b < nb; b += 64) {
    const float mb = bs[b * 2];
    const float sb = bs[b * 2 + 1];
    const float nm = fmaxf(m, mb);
    s = s * __expf(m - nm) + sb * __expf(mb - nm);
    m = nm;
  }
#pragma unroll
  for (int o = 32; o > 0; o >>= 1) {
    const float mo = __shfl_xor(m, o);
    const float so = __shfl_xor(s, o);
    const float nm = fmaxf(m, mo);
    s = s * __expf(m - nm) + so * __expf(mo - nm);
    m = nm;
  }
  if (l == 0) {
    mstat[sec * NT + c] = m;
    istat[sec * NT + c] = 1.f / s;
  }
}

// ------------------------------- MEGA kernels ------------------------------
// mega1: enc1 + GAT L1 projections + atomic-free csr_scatter (tail).
__global__ __launch_bounds__(256) void mega1(
    const u16* A0, const float* B0, float* P0,
    const u16* A1, const float* B1, float* P1,
    GP l, GP r,
    const int* ei, const int* row_ptr, const int* pos, int* csr_src) {
  __shared__ __align__(16) char smem[20480];
  const int bid = blockIdx.x;
  if (bid < ENC1B) {
    dev_enc1(A0, B0, P0, A1, B1, P1, bid, smem);
  } else if (bid < ENC1B + 2500) {
    const int sub = bid - ENC1B;        // 0..2499
    const GP& g = (sub >= 1250) ? r : l;
    const int rem = sub % 1250;
    dev_gemm_bt(g, rem % 2, rem / 2, smem);
  } else {
    dev_csr_scatter(ei, row_ptr, pos, csr_src, bid - ENC1B - 2500);
  }
}

__global__ __launch_bounds__(256) void mega2(
    const float* PG, int nzG, const float* bg, const float* gg, const float* beg, u16* og,
    const float* PP, int nzP, const float* bp, const float* gp, const float* bep, u16* op,
    const u16* xl, const u16* xr, const float* att, const float* bias,
    const int* row_ptr, const int* csr_src, u16* out_b) {
  __shared__ float red[256];
  const int bid = blockIdx.x;
  if (bid < 2 * TH)
    dev_bn_part(bid, PG, nzG, bg, gg, beg, og, PP, nzP, bp, gp, bep, op, red);
  else
    dev_gat<HID>(xl, xr, att, bias, row_ptr, csr_src, out_b, bid - 2 * TH);
}

__global__ __launch_bounds__(256) void mega3(GP eg, GP ep, GP l, GP r) {
  __shared__ __align__(16) char smem[20480];
  const int bid = blockIdx.x;
  if (bid < 64) {
    const int z = bid >> 5, rem = bid & 31;
    dev_gemm_bt(z ? ep : eg, rem & 7, rem >> 3, smem);
  } else {
    const int sub = bid - 64;
    const GP& g = (sub >= 625) ? r : l;
    dev_gemm_bt(g, 0, sub % 625, smem);
  }
}

__global__ __launch_bounds__(256) void mega4(
    const float* Hg, const float* bg, const float* gg, const float* beg, u16* og,
    const float* Hp, const float* bp, const float* gp, const float* bep, u16* op,
    const u16* xl, const u16* xr, const float* att, const float* bias,
    const int* row_ptr, const int* csr_src, u16* out_b) {
  __shared__ float red[256];
  const int bid = blockIdx.x;
  if (bid < 2 * TH)
    dev_bn2(bid, Hg, bg, gg, beg, og, Hp, bp, gp, bep, op, red);
  else
    dev_gat<EMB>(xl, xr, att, bias, row_ptr, csr_src, out_b, bid - 2 * TH);
}

__global__ __launch_bounds__(256) void mega5(GP hg, GP hp, GP tg, GP tp) {
  __shared__ __align__(16) char smem[20480];
  const int bid = blockIdx.x;
  if (bid < 32) {
    const int z = bid >> 4, rem = bid & 15;
    dev_gemm_bt(z ? hp : hg, rem & 3, rem >> 2, smem);
  } else {
    const int sub = bid - 32;
    const GP& g = (sub >= 876) ? tp : tg;
    const int rem = sub % 876;
    dev_gemm_bt(g, rem & 1, rem >> 1, smem);
  }
}

// mega6: row_kl || col_stats (counted) || col_merge (spins on count).
// Grid = 512 + 438 + 200 = 1150 blocks x 128 thr — far below co-residency
// capacity, so the counter barrier cannot deadlock.
__global__ __launch_bounds__(128) void mega6(
    const float* mld, const float* mlj, const float* mu_b, const float* ls_b,
    u16* thd, u16* thj, float* kl_out,
    const float* Lg, const float* Lp, float* bstats,
    int* cnt, int nbG, int nbP, float* mstat, float* istat) {
  __shared__ float red[128];
  const int bid = blockIdx.x;
  if (bid < 2 * BATCH) {
    dev_row_kl(bid % BATCH, bid / BATCH, mld, mlj, mu_b, ls_b, thd, thj, kl_out, red);
  } else if (bid < 2 * BATCH + 2 * NBMAX) {
    const int sub = bid - 2 * BATCH;
    dev_col_stats(sub % NBMAX, sub / NBMAX, Lg, Lp, bstats);
    __syncthreads();                       // all stores issued+complete (wave waitcnt)
    if (threadIdx.x == 0) {
      __threadfence();
      atomicAdd(cnt, 1);
    }
  } else {
    if (threadIdx.x == 0) {
      while (atomicAdd(cnt, 0) < 2 * NBMAX) ;
    }
    __syncthreads();
    const int sub = bid - 2 * BATCH - 2 * NBMAX;   // 0..2*NT-1
    if (threadIdx.x < 64)
      dev_col_merge(sub % NT, sub / NT, bstats, nbG, nbP, mstat, istat);
  }
}

// ---------------------------- remaining kernels ----------------------------
__global__ __launch_bounds__(256) void beta_norm(
    const float* __restrict__ Lg, const float* __restrict__ Lp,
    const float* __restrict__ mstat, const float* __restrict__ istat,
    u16* __restrict__ og, u16* __restrict__ op) {
  const float* L = blockIdx.y ? Lp : Lg;
  const int M = blockIdx.y ? NUM_PEAK : NUM_GENE;
  const float* mxg = mstat + blockIdx.y * NT;
  const float* ivg = istat + blockIdx.y * NT;
  u16* o = blockIdx.y ? op : og;
  __shared__ float mx[NT], inv[NT];
  for (int i = threadIdx.x; i < NT; i += 256) { mx[i] = mxg[i]; inv[i] = ivg[i]; }
  __syncthreads();
  const size_t total = (size_t)M * NTP;
  size_t i = (size_t)blockIdx.x * 256 + threadIdx.x;
  const size_t stride = (size_t)gridDim.x * 256;
  for (; i < total; i += stride) {
    const int c = (int)(i & (NTP - 1));
    u16 v = 0;
    if (c < NT) {
      const size_t r = i >> 7;
      v = f2bf(__expf(L[r * NT + c] - mx[c]) * inv[c]);
    }
    o[i] = v;
  }
}

__global__ __launch_bounds__(256) void recon_fused(
    const u16* __restrict__ thg, const u16* __restrict__ betag,
    const float* __restrict__ Xg, int Ng, int tiles_g,
    const u16* __restrict__ thp, const u16* __restrict__ betap,
    const float* __restrict__ Xp, int Np, float* __restrict__ partials) {
  __shared__ float pred[64][65];
  __shared__ float wsum[4];
  int ct = blockIdx.x;
  const u16* A; const u16* B; const float* X; int N;
  if (ct < tiles_g) { A = thg; B = betag; X = Xg; N = Ng; }
  else { ct -= tiles_g; A = thp; B = betap; X = Xp; N = Np; }
  const int bm = blockIdx.y * 64, bn = ct * 64;
  const int tid = threadIdx.x, w = tid >> 6, lane = tid & 63;
  const int wm = (w >> 1) * 32, wn = (w & 1) * 32;
  const int fr = lane & 15, ks = (lane >> 4) * 8;
  const u16* Ar0 = A + (size_t)(bm + wm + fr) * NTP;
  const u16* Ar1 = A + (size_t)(bm + wm + 16 + fr) * NTP;
  bf16x8 a0[4], a1[4];
#pragma unroll
  for (int kt = 0; kt < 4; ++kt) {
    a0[kt] = *(const bf16x8*)(Ar0 + kt * 32 + ks);
    a1[kt] = *(const bf16x8*)(Ar1 + kt * 32 + ks);
  }
  const int gn0 = min(bn + wn + fr, N - 1);
  const int gn1 = min(bn + wn + 16 + fr, N - 1);
  const u16* Br0 = B + (size_t)gn0 * NTP;
  const u16* Br1 = B + (size_t)gn1 * NTP;
  f32x4 acc[2][2] = {};
#pragma unroll
  for (int kt = 0; kt < 4; ++kt) {
    bf16x8 b0 = *(const bf16x8*)(Br0 + kt * 32 + ks);
    bf16x8 b1 = *(const bf16x8*)(Br1 + kt * 32 + ks);
    acc[0][0] = __builtin_amdgcn_mfma_f32_16x16x32_bf16(a0[kt], b0, acc[0][0], 0, 0, 0);
    acc[0][1] = __builtin_amdgcn_mfma_f32_16x16x32_bf16(a0[kt], b1, acc[0][1], 0, 0, 0);
    acc[1][0] = __builtin_amdgcn_mfma_f32_16x16x32_bf16(a1[kt], b0, acc[1][0], 0, 0, 0);
    acc[1][1] = __builtin_amdgcn_mfma_f32_16x16x32_bf16(a1[kt], b1, acc[1][1], 0, 0, 0);
  }
#pragma unroll
  for (int fi = 0; fi < 2; ++fi)
#pragma unroll
    for (int fj = 0; fj < 2; ++fj)
#pragma unroll
      for (int r = 0; r < 4; ++r)
        pred[wm + fi * 16 + (lane >> 4) * 4 + r][wn + fj * 16 + fr] = acc[fi][fj][r];
  __syncthreads();
  float local = 0.f;
  if (bn + 64 <= N) {
#pragma unroll
    for (int k = 0; k < 4; ++k) {
      const int j = k * 1024 + tid * 4;
      const int row = j >> 6, col = j & 63;
      const float4 xv = *(const float4*)(X + (size_t)(bm + row) * N + bn + col);
      local += xv.x * __logf(pred[row][col + 0] + 1e-6f);
      local += xv.y * __logf(pred[row][col + 1] + 1e-6f);
      local += xv.z * __logf(pred[row][col + 2] + 1e-6f);
      local += xv.w * __logf(pred[row][col + 3] + 1e-6f);
    }
  } else {
#pragma unroll
    for (int k = 0; k < 16; ++k) {
      const int idx = k * 256 + tid, row = idx >> 6, col = idx & 63;
      if (bn + col < N)
        local += X[(size_t)(bm + row) * N + bn + col] * __logf(pred[row][col] + 1e-6f);
    }
  }
  for (int o = 32; o > 0; o >>= 1) local += __shfl_down(local, o);
  if (lane == 0) wsum[w] = local;
  __syncthreads();
  if (tid == 0)
    partials[(size_t)blockIdx.y * gridDim.x + blockIdx.x] =
        wsum[0] + wsum[1] + wsum[2] + wsum[3];
}

__global__ __launch_bounds__(256) void final_recon(
    const float* __restrict__ partials, int n, float* __restrict__ out) {
  float s = 0.f;
  for (int i = threadIdx.x; i < n; i += 256) s += partials[i];
  __shared__ float red[256];
  red[threadIdx.x] = s; __syncthreads();
  for (int o = 128; o > 0; o >>= 1) {
    if (threadIdx.x < o) red[threadIdx.x] += red[threadIdx.x + o];
    __syncthreads();
  }
  if (threadIdx.x == 0) out[0] = -red[0] * (1.f / BATCH);
}

// ---------------------------------------------------------------------------
extern "C" void kernel_launch(void* const* d_in, const int* in_sizes, int n_in,
                              void* d_out, int out_size, void* d_ws, size_t ws_size,
                              hipStream_t stream) {
  const float* Gene  = (const float*)d_in[0];
  const float* GeneN = (const float*)d_in[1];
  const float* Peak  = (const float*)d_in[2];
  const float* PeakN = (const float*)d_in[3];
  const float* feat  = (const float*)d_in[4];
  const float* Wl1 = (const float*)d_in[5];  const float* bl1 = (const float*)d_in[6];
  const float* Wr1 = (const float*)d_in[7];  const float* br1 = (const float*)d_in[8];
  const float* att1 = (const float*)d_in[9]; const float* bias1 = (const float*)d_in[10];
  const float* Wl2 = (const float*)d_in[11]; const float* bl2 = (const float*)d_in[12];
  const float* Wr2 = (const float*)d_in[13]; const float* br2 = (const float*)d_in[14];
  const float* att2 = (const float*)d_in[15]; const float* bias2 = (const float*)d_in[16];
  const float* gW1 = (const float*)d_in[17]; const float* gb1 = (const float*)d_in[18];
  const float* gg1 = (const float*)d_in[19]; const float* gbe1 = (const float*)d_in[20];
  const float* gW2 = (const float*)d_in[21]; const float* gb2 = (const float*)d_in[22];
  const float* gg2 = (const float*)d_in[23]; const float* gbe2 = (const float*)d_in[24];
  const float* pW1 = (const float*)d_in[25]; const float* pb1 = (const float*)d_in[26];
  const float* pg1 = (const float*)d_in[27]; const float* pbe1 = (const float*)d_in[28];
  const float* pW2 = (const float*)d_in[29]; const float* pb2 = (const float*)d_in[30];
  const float* pg2 = (const float*)d_in[31]; const float* pbe2 = (const float*)d_in[32];
  const float* mu_W = (const float*)d_in[33]; const float* mu_b = (const float*)d_in[34];
  const float* ls_W = (const float*)d_in[35]; const float* ls_b = (const float*)d_in[36];
  const float* alphas_W = (const float*)d_in[37];
  const float* alphas_star_W = (const float*)d_in[38];
  const int* ei = (const int*)d_in[39];
  float* out = (float*)d_out;
  (void)in_sizes; (void)n_in; (void)ws_size;

  // ---- workspace layout (bytes) ----
  char* base = (char*)d_ws;
  size_t off = 0;
  auto A = [&](size_t bytes) { void* p = base + off; off += (bytes + 255) & ~(size_t)255; return p; };
  int* deg     = (int*)A((size_t)N_NODES * 4);      // deg + cnt zeroed together
  int* cnt     = (int*)A(256);                      // cnt[0]=scan, cnt[64]=mega6
  int* row_ptr = (int*)A((size_t)(N_NODES + 1) * 4);
  int* bsum    = (int*)A((size_t)(SCAN_NB + 1) * 4);
  int* pos     = (int*)A((size_t)E_TOTAL * 4);
  int* csr_src = (int*)A((size_t)E_TOTAL * 4);
  float* CpartG = (float*)A((size_t)KSPG * TH * 256 * 4);
  float* CpartP = (float*)A((size_t)KSPP * TH * 256 * 4);
  float* h2g = (float*)A((size_t)BATCH * TH * 4);
  float* h2p = (float*)A((size_t)BATCH * TH * 4);
  u16* h1gb = (u16*)A((size_t)BATCH * TH * 2);
  u16* h2gb = (u16*)A((size_t)BATCH * TH * 2);
  u16* h1pb = (u16*)A((size_t)BATCH * TH * 2);
  u16* h2pb = (u16*)A((size_t)BATCH * TH * 2);
  float* ml_d = (float*)A((size_t)BATCH * NT2 * 4);
  float* ml_j = (float*)A((size_t)BATCH * NT2 * 4);
  u16* th_db = (u16*)A((size_t)BATCH * NTP * 2);
  u16* th_jb = (u16*)A((size_t)BATCH * NTP * 2);
  float* lgg = (float*)A((size_t)NUM_GENE * NT * 4);
  float* lgp = (float*)A((size_t)NUM_PEAK * NT * 4);
  u16* betagb = (u16*)A((size_t)NUM_GENE * NTP * 2);
  u16* betapb = (u16*)A((size_t)NUM_PEAK * NTP * 2);
  u16* featb = (u16*)A((size_t)N_NODES * EMB * 2);
  u16* gW2b = (u16*)A((size_t)TH * TH * 2);
  u16* pW2b = (u16*)A((size_t)TH * TH * 2);
  u16* mlWb = (u16*)A((size_t)NT2 * TH * 2);
  u16* Wl1b = (u16*)A((size_t)HID * EMB * 2);
  u16* Wr1b = (u16*)A((size_t)HID * EMB * 2);
  u16* Wl2b = (u16*)A((size_t)EMB * HID * 2);
  u16* Wr2b = (u16*)A((size_t)EMB * HID * 2);
  u16* aWb  = (u16*)A((size_t)NT * EMB * 2);
  u16* aSWb = (u16*)A((size_t)NT * EMB * 2);
  u16* agg1b = (u16*)A((size_t)N_NODES * HID * 2);
  u16* embb  = (u16*)A((size_t)N_NODES * EMB * 2);
  float* mstat = (float*)A(2 * NT * 4);
  float* istat = (float*)A(2 * NT * 4);
  float* bstats = (float*)A((size_t)2 * NT * NBMAX * 2 * 4);
  float* partials = (float*)A(4096 * 4);
  u16* xl1b = (u16*)A((size_t)N_NODES * HID * 2);
  u16* xr1b = (u16*)A((size_t)N_NODES * HID * 2);
  u16* xl2b = (u16*)A((size_t)N_NODES * EMB * 2);
  u16* xr2b = (u16*)A((size_t)N_NODES * EMB * 2);
  u16* GeneNb = (u16*)A((size_t)BATCH * KPG * 2);
  u16* PeakNb = (u16*)A((size_t)BATCH * KPP * 2);

  auto cdiv = [](int a, int b) { return (a + b - 1) / b; };
  auto Z = [&](void* p, size_t bytes) { hipMemsetAsync(p, 0, bytes, stream); };

  Z(d_out, (size_t)out_size * sizeof(float));
  Z(deg, (size_t)N_NODES * 4 + 256);               // deg + cnt

  // ---- megaA: deg_count(+pos) || cvt_pad || cvt_all ----
  int cvtallB;
  {
    CvtJobs J = {};
    int c = 0; u32 blocks = 0;
    auto add = [&](const float* s, u16* d, size_t n) {
      J.src[c] = s; J.dst[c] = d; J.n[c] = (u32)n; J.start[c] = blocks;
      blocks += (u32)((n + 2047) / 2048); ++c;
    };
    add(gW2, gW2b, (size_t)TH * TH);
    add(pW2, pW2b, (size_t)TH * TH);
    add(mu_W, mlWb, (size_t)NT * TH);
    add(ls_W, mlWb + (size_t)NT * TH, (size_t)NT * TH);
    add(feat, featb, (size_t)N_NODES * EMB);
    add(Wl1, Wl1b, (size_t)HID * EMB);
    add(Wr1, Wr1b, (size_t)HID * EMB);
    add(Wl2, Wl2b, (size_t)EMB * HID);
    add(Wr2, Wr2b, (size_t)EMB * HID);
    add(alphas_W, aWb, (size_t)NT * EMB);
    add(alphas_star_W, aSWb, (size_t)NT * EMB);
    J.count = c;
    cvtallB = (int)blocks;
    megaA<<<DEGB + PADGB + PADPB + cvtallB, 256, 0, stream>>>(
        ei, deg, pos, GeneN, GeneNb, PeakN, PeakNb, J);
  }

  // ---- single-launch scan (counter barrier) ----
  scan_fused<<<SCAN_NB, 256, 0, stream>>>(deg, bsum, row_ptr, cnt);

  // ---- mega1: enc1 + GAT L1 projections + atomic-free csr_scatter ----
  {
    GP l = {featb, Wl1b, nullptr, xl1b, bl1, N_NODES, HID, EMB};
    GP r = {featb, Wr1b, nullptr, xr1b, br1, N_NODES, HID, EMB};
    mega1<<<ENC1B + 2500 + DEGB, 256, 0, stream>>>(
        GeneNb, gW1, CpartG, PeakNb, pW1, CpartP, l, r,
        ei, row_ptr, pos, csr_src);
  }

  // ---- mega2: bn_part + gat<HID> ----
  mega2<<<2 * TH + N_NODES / 4, 256, 0, stream>>>(
      CpartG, KSPG, gb1, gg1, gbe1, h1gb,
      CpartP, KSPP, pb1, pg1, pbe1, h1pb,
      xl1b, xr1b, att1, bias1, row_ptr, csr_src, agg1b);

  // ---- mega3: enc L2 GEMM + GAT L2 projections ----
  {
    GP eg = {h1gb, gW2b, h2g, nullptr, nullptr, BATCH, TH, TH};
    GP ep = {h1pb, pW2b, h2p, nullptr, nullptr, BATCH, TH, TH};
    GP l  = {agg1b, Wl2b, nullptr, xl2b, bl2, N_NODES, EMB, HID};
    GP r  = {agg1b, Wr2b, nullptr, xr2b, br2, N_NODES, EMB, HID};
    mega3<<<64 + 1250, 256, 0, stream>>>(eg, ep, l, r);
  }

  // ---- mega4: bn2 + gat<EMB> ----
  mega4<<<2 * TH + N_NODES / 4, 256, 0, stream>>>(
      h2g, gb2, gg2, gbe2, h2gb,
      h2p, pb2, pg2, pbe2, h2pb,
      xl2b, xr2b, att2, bias2, row_ptr, csr_src, embb);

  // ---- mega5: heads GEMM + topic GEMM ----
  {
    GP hg = {h2gb, mlWb, ml_d, nullptr, nullptr, BATCH, NT2, TH};
    GP hp = {h2pb, mlWb, ml_j, nullptr, nullptr, BATCH, NT2, TH};
    GP tg = {embb + (size_t)NUM_PEAK * EMB, aWb, lgg, nullptr, nullptr, NUM_GENE, NT, EMB};
    GP tp = {embb, aSWb, lgp, nullptr, nullptr, NUM_PEAK, NT, EMB};
    mega5<<<32 + 2 * 2 * 438, 256, 0, stream>>>(hg, hp, tg, tp);
  }

  const int nbG = cdiv(NUM_GENE, CS_ROWS);   // 94
  const int nbP = cdiv(NUM_PEAK, CS_ROWS);   // 219

  // ---- mega6: row_kl_theta + col_stats + col_merge (counter barrier) ----
  mega6<<<2 * BATCH + 2 * NBMAX + 2 * NT, 128, 0, stream>>>(
      ml_d, ml_j, mu_b, ls_b, th_db, th_jb, out + 1, lgg, lgp, bstats,
      cnt + 64, nbG, nbP, mstat, istat);

  beta_norm<<<dim3(1024, 2), 256, 0, stream>>>(lgg, lgp, mstat, istat, betagb, betapb);

  // ---- fused preds + recon ----
  const int tiles_g = cdiv(NUM_GENE, 64);
  const int tiles_p = cdiv(NUM_PEAK, 64);
  const int tiles = tiles_g + tiles_p;
  recon_fused<<<dim3(tiles, 4), 256, 0, stream>>>(
      th_db, betagb, Gene, NUM_GENE, tiles_g,
      th_jb, betapb, Peak, NUM_PEAK, partials);
  final_recon<<<1, 256, 0, stream>>>(partials, tiles * 4, out);
}

// Round 29
// 329.244 us; speedup vs baseline: 1.0951x; 1.0951x over previous
//
#include <hip/hip_runtime.h>
#include <cstdint>
#include <cstddef>

using u16 = unsigned short;
using u32 = unsigned int;
typedef __attribute__((ext_vector_type(8))) short bf16x8;
typedef __attribute__((ext_vector_type(4))) float f32x4;

static constexpr int NUM_PEAK = 28000;
static constexpr int NUM_GENE = 12000;
static constexpr int N_NODES  = NUM_PEAK + NUM_GENE;   // 40000
static constexpr int N_EDGES  = 640000;
static constexpr int E_TOTAL  = N_EDGES + N_NODES;     // 680000
static constexpr int NT       = 100;
static constexpr int NT2      = 200;
static constexpr int NTP      = 128;
static constexpr int TH       = 512;
static constexpr int EMB      = 64;
static constexpr int HID      = 128;
static constexpr int BATCH    = 256;
static constexpr int SCAN_CHUNK = 1024;
static constexpr int SCAN_NB  = (N_NODES + SCAN_CHUNK - 1) / SCAN_CHUNK;  // 40
static constexpr int ENC_CH   = 1280;                  // enc1 k-chunk (20 x 64)
static constexpr int KPG      = 12032;
static constexpr int KPP      = 28032;
static constexpr int KSPG     = (NUM_GENE + ENC_CH - 1) / ENC_CH;  // 10
static constexpr int KSPP     = (NUM_PEAK + ENC_CH - 1) / ENC_CH;  // 22
static constexpr int ENC1B    = 8 * 4 * (KSPG + KSPP);             // 1024
static constexpr int DEGB     = (E_TOTAL + 255) / 256;             // 2657
static constexpr int PADGB    = BATCH * KPG / 8 / 256;             // 1504
static constexpr int PADPB    = BATCH * KPP / 8 / 256;             // 3504
static constexpr int CS_ROWS  = 128;
static constexpr int NBMAX    = (NUM_PEAK + CS_ROWS - 1) / CS_ROWS;  // 219
#define BN_EPS 1e-5f

__device__ __forceinline__ u16 f2bf(float f) {
  u32 b = __float_as_uint(f);
  return (u16)((b + 0x7FFFu + ((b >> 16) & 1u)) >> 16);
}

// ---------------------------------------------------------------------------
struct CvtJobs {
  const float* src[12];
  u16* dst[12];
  u32 n[12];
  u32 start[12];
  int count;
};

__device__ void dev_cvt_all(const CvtJobs& J, int bid) {
  int seg = 0;
  while (seg + 1 < J.count && bid >= (int)J.start[seg + 1]) ++seg;
  const float* __restrict__ src = J.src[seg];
  u16* __restrict__ dst = J.dst[seg];
  const u32 n = J.n[seg];
  const u32 i = (u32)(bid - J.start[seg]) * 2048u + threadIdx.x * 8u;
  if (i + 8 <= n) {
    float4 a = *(const float4*)(src + i);
    float4 b = *(const float4*)(src + i + 4);
    ushort4 o0{f2bf(a.x), f2bf(a.y), f2bf(a.z), f2bf(a.w)};
    ushort4 o1{f2bf(b.x), f2bf(b.y), f2bf(b.z), f2bf(b.w)};
    *(ushort4*)(dst + i) = o0;
    *(ushort4*)(dst + i + 4) = o1;
  } else {
    for (u32 j = i; j < n; ++j) dst[j] = f2bf(src[j]);
  }
}

__device__ void dev_cvt_pad(const float* __restrict__ src, u16* __restrict__ dst,
                            int K, int Kp, int bid) {
  const size_t i = ((size_t)bid * 256 + threadIdx.x) * 8;   // always < BATCH*Kp
  const int col = (int)(i % Kp);
  const size_t row = i / Kp;
  ushort4 o0{0, 0, 0, 0}, o1{0, 0, 0, 0};
  if (col + 8 <= K) {
    const float* s = src + row * K + col;
    float4 a = *(const float4*)s;
    float4 b = *(const float4*)(s + 4);
    o0 = ushort4{f2bf(a.x), f2bf(a.y), f2bf(a.z), f2bf(a.w)};
    o1 = ushort4{f2bf(b.x), f2bf(b.y), f2bf(b.z), f2bf(b.w)};
  }
  *(ushort4*)(dst + i) = o0;
  *(ushort4*)(dst + i + 4) = o1;
}

// deg_count also records each edge's slot within its destination's bucket,
// so the later scatter needs NO atomic.
__device__ void dev_deg_count(const int* __restrict__ ei, int* __restrict__ deg,
                              int* __restrict__ pos, int bid) {
  const int e = bid * 256 + threadIdx.x;
  if (e >= E_TOTAL) return;
  const int d = (e < N_EDGES) ? ei[N_EDGES + e] : e - N_EDGES;
  pos[e] = atomicAdd(&deg[d], 1);
}

__device__ void dev_csr_scatter(const int* __restrict__ ei,
                                const int* __restrict__ row_ptr,
                                const int* __restrict__ pos,
                                int* __restrict__ csr_src, int bid) {
  const int e = bid * 256 + threadIdx.x;
  if (e >= E_TOTAL) return;
  int s, d;
  if (e < N_EDGES) { s = ei[e]; d = ei[N_EDGES + e]; }
  else { s = d = e - N_EDGES; }
  csr_src[row_ptr[d] + pos[e]] = s;      // atomic-free
}

// megaA: deg_count || cvt_pad(gene) || cvt_pad(peak) || cvt_all
__global__ __launch_bounds__(256) void megaA(
    const int* ei, int* deg, int* pos,
    const float* GeneN, u16* GeneNb, const float* PeakN, u16* PeakNb,
    CvtJobs J) {
  const int bid = blockIdx.x;
  if (bid < DEGB) dev_deg_count(ei, deg, pos, bid);
  else if (bid < DEGB + PADGB) dev_cvt_pad(GeneN, GeneNb, NUM_GENE, KPG, bid - DEGB);
  else if (bid < DEGB + PADGB + PADPB) dev_cvt_pad(PeakN, PeakNb, NUM_PEAK, KPP, bid - DEGB - PADGB);
  else dev_cvt_all(J, bid - DEGB - PADGB - PADPB);
}

// ---------------------------------------------------------------------------
// Device GEMM (dual-use): C(M,N)=A@B^T, 64x64 tile, 4 waves, BK=32.
// ---------------------------------------------------------------------------
struct GP {
  const u16* A; const u16* B; float* C; u16* Cb; const float* bias;
  int M, N, K;
};

__device__ void dev_gemm_bt(const GP g, int bxx, int byy, char* smem) {
  u16 (*As)[40] = (u16(*)[40])smem;
  u16 (*Bs)[40] = (u16(*)[40])(smem + 64 * 40 * 2);
  const int M = g.M, N = g.N, K = g.K;
  const int tid = threadIdx.x;
  const int bm = byy * 64, bn = bxx * 64;
  if (bm >= M || bn >= N) return;
  const int w = tid >> 6, lane = tid & 63;
  const int wm = (w >> 1) * 32, wn = (w & 1) * 32;
  const int fr = lane & 15;
  const int ks = (lane >> 4) * 8;
  const int srow = tid >> 2, sseg = (tid & 3) * 8;
  f32x4 acc[2][2] = {};
  for (int kt = 0; kt < K; kt += 32) {
    const int gk = kt + sseg;
    {
      const int gm = bm + srow;
      bf16x8 v = {0, 0, 0, 0, 0, 0, 0, 0};
      if (gm < M) v = *(const bf16x8*)(g.A + (size_t)gm * K + gk);
      *(bf16x8*)&As[srow][sseg] = v;
    }
    {
      const int gn = bn + srow;
      bf16x8 v = {0, 0, 0, 0, 0, 0, 0, 0};
      if (gn < N) v = *(const bf16x8*)(g.B + (size_t)gn * K + gk);
      *(bf16x8*)&Bs[srow][sseg] = v;
    }
    __syncthreads();
    bf16x8 a0 = *(const bf16x8*)&As[wm + fr][ks];
    bf16x8 a1 = *(const bf16x8*)&As[wm + 16 + fr][ks];
    bf16x8 b0 = *(const bf16x8*)&Bs[wn + fr][ks];
    bf16x8 b1 = *(const bf16x8*)&Bs[wn + 16 + fr][ks];
    acc[0][0] = __builtin_amdgcn_mfma_f32_16x16x32_bf16(a0, b0, acc[0][0], 0, 0, 0);
    acc[0][1] = __builtin_amdgcn_mfma_f32_16x16x32_bf16(a0, b1, acc[0][1], 0, 0, 0);
    acc[1][0] = __builtin_amdgcn_mfma_f32_16x16x32_bf16(a1, b0, acc[1][0], 0, 0, 0);
    acc[1][1] = __builtin_amdgcn_mfma_f32_16x16x32_bf16(a1, b1, acc[1][1], 0, 0, 0);
    __syncthreads();
  }
#pragma unroll
  for (int fi = 0; fi < 2; ++fi)
#pragma unroll
    for (int fj = 0; fj < 2; ++fj)
#pragma unroll
      for (int r = 0; r < 4; ++r) {
        const int row = bm + wm + fi * 16 + (lane >> 4) * 4 + r;
        const int col = bn + wn + fj * 16 + fr;
        if (row < M && col < N) {
          const float v = acc[fi][fj][r];
          if (g.Cb) g.Cb[(size_t)row * N + col] = f2bf(v + (g.bias ? g.bias[col] : 0.f));
          else g.C[(size_t)row * N + col] = v + (g.bias ? g.bias[col] : 0.f);
        }
      }
}

// ---------------------------------------------------------------------------
// Device encoder-L1 GEMM (v9): 64x64 tile, stores fp32 partial slices.
// ---------------------------------------------------------------------------
__device__ __forceinline__ int swz64(int row, int colu16) {
  return row * 64 + ((((colu16 >> 3) ^ row) & 7) << 3) + (colu16 & 7);
}

__device__ void dev_enc1(
    const u16* __restrict__ A0, const float* __restrict__ B0, float* __restrict__ P0,
    const u16* __restrict__ A1, const float* __restrict__ B1, float* __restrict__ P1,
    int bid, char* smem) {
  const int cpx = ENC1B >> 3;
  const int f2 = (bid & 7) * cpx + (bid >> 3);
  const int bx = f2 % 8;
  const int by = (f2 / 8) % 4;
  const int bz = f2 / 32;
  const bool second = (bz >= KSPG);
  const u16* __restrict__ A = second ? A1 : A0;
  const float* __restrict__ B = second ? B1 : B0;
  float* __restrict__ P = second ? P1 : P0;
  const int K = second ? NUM_PEAK : NUM_GENE;
  const int Kp = second ? KPP : KPG;
  const int zz = second ? bz - KSPG : bz;
  const int k0 = zz * ENC_CH;
  const int k1 = min(K, k0 + ENC_CH);
  u16* As = (u16*)smem;
  u16* Bs = (u16*)(smem + 8192);
  const int tid = threadIdx.x;
  const int bm = by * 64;
  const int bn = bx * 64;
  const int w = tid >> 6, lane = tid & 63;
  const int wm = w * 16;
  const int fr = lane & 15, g = lane >> 4;
  const int ar = tid >> 2, acol = (tid & 3) * 16;
  const int br = tid >> 2, bcol = (tid & 3) * 16;
  const u16* Abase = A + (size_t)(bm + ar) * Kp + acol;
  const float* Bbase = B + (size_t)(bn + br) * K + bcol;

  bf16x8 rA0, rA1;
  float4 rB0, rB1, rB2, rB3;
  auto LD = [&](int kt) {
    const u16* sa = Abase + kt;
    rA0 = *(const bf16x8*)(sa);
    rA1 = *(const bf16x8*)(sa + 8);
    if (kt + bcol + 16 <= K) {
      const float* sb = Bbase + kt;
      rB0 = *(const float4*)(sb);
      rB1 = *(const float4*)(sb + 4);
      rB2 = *(const float4*)(sb + 8);
      rB3 = *(const float4*)(sb + 12);
    } else {
      rB0 = float4{0.f, 0.f, 0.f, 0.f}; rB1 = rB0; rB2 = rB0; rB3 = rB0;
    }
  };
  auto ST = [&]() {
    *(bf16x8*)&As[swz64(ar, acol)] = rA0;
    *(bf16x8*)&As[swz64(ar, acol + 8)] = rA1;
    ushort4 p0{f2bf(rB0.x), f2bf(rB0.y), f2bf(rB0.z), f2bf(rB0.w)};
    ushort4 p1{f2bf(rB1.x), f2bf(rB1.y), f2bf(rB1.z), f2bf(rB1.w)};
    ushort4 p2{f2bf(rB2.x), f2bf(rB2.y), f2bf(rB2.z), f2bf(rB2.w)};
    ushort4 p3{f2bf(rB3.x), f2bf(rB3.y), f2bf(rB3.z), f2bf(rB3.w)};
    const int b0 = swz64(br, bcol);
    const int b1 = swz64(br, bcol + 8);
    *(ushort4*)&Bs[b0] = p0;
    *(ushort4*)&Bs[b0 + 4] = p1;
    *(ushort4*)&Bs[b1] = p2;
    *(ushort4*)&Bs[b1 + 4] = p3;
  };

  f32x4 acc[4] = {};
  LD(k0);
  ST();
  for (int kt = k0; kt < k1; kt += 64) {
    __syncthreads();
    const bool more = (kt + 64 < k1);
    if (more) LD(kt + 64);
#pragma unroll
    for (int s = 0; s < 2; ++s) {
      const int kc = s * 32 + g * 8;
      bf16x8 a = *(const bf16x8*)&As[swz64(wm + fr, kc)];
#pragma unroll
      for (int fj = 0; fj < 4; ++fj) {
        bf16x8 b = *(const bf16x8*)&Bs[swz64(fj * 16 + fr, kc)];
        acc[fj] = __builtin_amdgcn_mfma_f32_16x16x32_bf16(a, b, acc[fj], 0, 0, 0);
      }
    }
    __syncthreads();
    if (more) ST();
  }
  float* Pz = P + (size_t)zz * TH * 256;
  const int row = bm + wm + g * 4;
#pragma unroll
  for (int fj = 0; fj < 4; ++fj) {
    const int col = bn + fj * 16 + fr;
    *(f32x4*)&Pz[(size_t)col * 256 + row] = acc[fj];
  }
}

// ---------------------------------------------------------------------------
template <int C>
__device__ void dev_gat(
    const u16* __restrict__ xl, const u16* __restrict__ xr,
    const float* __restrict__ att, const float* __restrict__ bias,
    const int* __restrict__ row_ptr, const int* __restrict__ csr_src,
    u16* __restrict__ out_b, int blk) {
  constexpr int CPL = C / 8;
  constexpr int W = CPL / 2;
  const int lane = threadIdx.x & 63;
  const int g = lane >> 3, li = lane & 7;
  const int d = blk * 4 + ((int)threadIdx.x >> 6);
  if (d >= N_NODES) return;
  const int c0 = li * CPL;
  float xrv[CPL], attv[CPL], acc[CPL];
  {
    const u32* xrw = (const u32*)(xr + (size_t)d * C + c0);
#pragma unroll
    for (int i = 0; i < W; ++i) {
      const u32 wv = xrw[i];
      xrv[2 * i]     = __uint_as_float(wv << 16);
      xrv[2 * i + 1] = __uint_as_float(wv & 0xffff0000u);
    }
  }
#pragma unroll
  for (int i = 0; i < CPL; ++i) { attv[i] = att[c0 + i]; acc[i] = 0.f; }
  float m = -INFINITY, den = 0.f;
  const int end = row_ptr[d + 1];
  int p = row_ptr[d] + g;
  int s = (p < end) ? csr_src[p] : 0;
  u32 w[W];
  {
    const u32* sw = (const u32*)(xl + (size_t)s * C + c0);
#pragma unroll
    for (int i = 0; i < W; ++i) w[i] = sw[i];
  }
  while (p < end) {
    const int sn = (p + 8 < end) ? csr_src[p + 8] : 0;
    u32 wn[W];
    {
      const u32* sw = (const u32*)(xl + (size_t)sn * C + c0);
#pragma unroll
      for (int i = 0; i < W; ++i) wn[i] = sw[i];
    }
    float xlv[CPL];
#pragma unroll
    for (int i = 0; i < W; ++i) {
      xlv[2 * i]     = __uint_as_float(w[i] << 16);
      xlv[2 * i + 1] = __uint_as_float(w[i] & 0xffff0000u);
    }
    float part = 0.f;
#pragma unroll
    for (int i = 0; i < CPL; ++i) {
      float x = xlv[i] + xrv[i];
      x = (x > 0.f) ? x : 0.2f * x;
      part += x * attv[i];
    }
    part += __shfl_xor(part, 1);
    part += __shfl_xor(part, 2);
    part += __shfl_xor(part, 4);
    const float nm = fmaxf(m, part);
    const float scale = __expf(m - nm);
    const float ex = __expf(part - nm);
    den = den * scale + ex;
#pragma unroll
    for (int i = 0; i < CPL; ++i) acc[i] = acc[i] * scale + ex * xlv[i];
    m = nm;
    p += 8;
#pragma unroll
    for (int i = 0; i < W; ++i) w[i] = wn[i];
  }
  float M = m;
  M = fmaxf(M, __shfl_xor(M, 8));
  M = fmaxf(M, __shfl_xor(M, 16));
  M = fmaxf(M, __shfl_xor(M, 32));
  const float gs = __expf(m - M);
  den *= gs;
  den += __shfl_xor(den, 8);
  den += __shfl_xor(den, 16);
  den += __shfl_xor(den, 32);
  const float inv = 1.f / (den + 1e-16f);
  float va[CPL];
#pragma unroll
  for (int i = 0; i < CPL; ++i) {
    float a = acc[i] * gs;
    a += __shfl_xor(a, 8);
    a += __shfl_xor(a, 16);
    a += __shfl_xor(a, 32);
    va[i] = a;
  }
  if (g == 0) {
    u32* dst = (u32*)(out_b + (size_t)d * C + c0);
#pragma unroll
    for (int i = 0; i < W; ++i) {
      const u16 lo = f2bf(fmaxf(va[2 * i] * inv + bias[c0 + 2 * i], 0.f));
      const u16 hi = f2bf(fmaxf(va[2 * i + 1] * inv + bias[c0 + 2 * i + 1], 0.f));
      dst[i] = (u32)lo | ((u32)hi << 16);
    }
  }
}

__device__ void dev_bn_body(float v, const float* gma, const float* be, int c,
                            u16* ob, float* red) {
  const int r = threadIdx.x;
  red[r] = v; __syncthreads();
  for (int s = BATCH / 2; s > 0; s >>= 1) { if (r < s) red[r] += red[r + s]; __syncthreads(); }
  const float mean = red[0] * (1.f / BATCH);
  __syncthreads();
  const float d = v - mean;
  red[r] = d * d; __syncthreads();
  for (int s = BATCH / 2; s > 0; s >>= 1) { if (r < s) red[r] += red[r + s]; __syncthreads(); }
  const float var = red[0] * (1.f / BATCH);
  ob[(size_t)r * TH + c] = f2bf(d * rsqrtf(var + BN_EPS) * gma[c] + be[c]);
}

__device__ void dev_bn_part(
    int cg, const float* __restrict__ PG, int nzG, const float* bg,
    const float* gg, const float* beg, u16* og,
    const float* __restrict__ PP, int nzP, const float* bp,
    const float* gp, const float* bep, u16* op, float* red) {
  int c = cg;
  const float *P, *b, *gma, *be; u16* ob; int nz;
  if (c < TH) { P = PG; nz = nzG; b = bg; gma = gg; be = beg; ob = og; }
  else { c -= TH; P = PP; nz = nzP; b = bp; gma = gp; be = bep; ob = op; }
  const int r = threadIdx.x;
  float v = 0.f;
  const float* base = P + (size_t)c * 256 + r;
  for (int z = 0; z < nz; ++z) v += base[(size_t)z * TH * 256];
  v = fmaxf(v + b[c], 0.f);
  dev_bn_body(v, gma, be, c, ob, red);
}

__device__ void dev_bn2(
    int cg, const float* __restrict__ Hg, const float* bg,
    const float* gg, const float* beg, u16* og,
    const float* __restrict__ Hp, const float* bp,
    const float* gp, const float* bep, u16* op, float* red) {
  int c = cg;
  const float *H, *b, *gma, *be; u16* ob;
  if (c < TH) { H = Hg; b = bg; gma = gg; be = beg; ob = og; }
  else { c -= TH; H = Hp; b = bp; gma = gp; be = bep; ob = op; }
  const int r = threadIdx.x;
  float v = fmaxf(H[(size_t)r * TH + c] + b[c], 0.f);
  dev_bn_body(v, gma, be, c, ob, red);
}

__device__ void dev_row_kl(
    int b, int which, const float* __restrict__ mld, const float* __restrict__ mlj,
    const float* mu_b, const float* ls_b,
    u16* thd, u16* thj, float* kl_out, float* red) {
  const float* ml = which ? mlj : mld;
  u16* thb = which ? thj : thd;
  const int t = threadIdx.x;
  const bool act = (t < NT);
  float mu = 0.f, ls = 0.f, term = 0.f;
  if (act) {
    mu = ml[(size_t)b * NT2 + t] + mu_b[t];
    ls = 2.f * (ml[(size_t)b * NT2 + NT + t] + ls_b[t]);
    term = 1.f + ls - mu * mu - expf(ls);
  }
  red[t] = act ? term : 0.f; __syncthreads();
  for (int s = 64; s > 0; s >>= 1) { if (t < s) red[t] += red[t + s]; __syncthreads(); }
  if (t == 0) atomicAdd(kl_out, -0.5f * red[0] * (1.f / BATCH));
  __syncthreads();
  red[t] = act ? mu : -INFINITY; __syncthreads();
  for (int s = 64; s > 0; s >>= 1) { if (t < s) red[t] = fmaxf(red[t], red[t + s]); __syncthreads(); }
  const float mx = red[0];
  __syncthreads();
  const float e = act ? expf(mu - mx) : 0.f;
  red[t] = e; __syncthreads();
  for (int s = 64; s > 0; s >>= 1) { if (t < s) red[t] += red[t + s]; __syncthreads(); }
  thb[(size_t)b * NTP + t] = act ? f2bf(e / red[0]) : (u16)0;
}

__device__ void dev_col_stats(
    int bx, int sec, const float* __restrict__ Lg, const float* __restrict__ Lp,
    float* __restrict__ bstats) {
  const float* L = sec ? Lp : Lg;
  const int M = sec ? NUM_PEAK : NUM_GENE;
  const int r0 = bx * CS_ROWS;
  const int c = threadIdx.x;
  if (c >= NT || r0 >= M) return;
  const int rend = min(r0 + CS_ROWS, M);
  float m = -INFINITY, s = 0.f;
  for (int r = r0; r < rend; ++r) {
    const float v = L[(size_t)r * NT + c];
    const float nm = fmaxf(m, v);
    s = s * __expf(m - nm) + __expf(v - nm);
    m = nm;
  }
  float* bs = bstats + (((size_t)sec * NT + c) * NBMAX + bx) * 2;
  bs[0] = m;
  bs[1] = s;
}

// ------------------------------- MEGA kernels ------------------------------
// mega1: enc1 + GAT L1 projections + atomic-free csr_scatter (tail).
__global__ __launch_bounds__(256) void mega1(
    const u16* A0, const float* B0, float* P0,
    const u16* A1, const float* B1, float* P1,
    GP l, GP r,
    const int* ei, const int* row_ptr, const int* pos, int* csr_src) {
  __shared__ __align__(16) char smem[20480];
  const int bid = blockIdx.x;
  if (bid < ENC1B) {
    dev_enc1(A0, B0, P0, A1, B1, P1, bid, smem);
  } else if (bid < ENC1B + 2500) {
    const int sub = bid - ENC1B;        // 0..2499
    const GP& g = (sub >= 1250) ? r : l;
    const int rem = sub % 1250;
    dev_gemm_bt(g, rem % 2, rem / 2, smem);
  } else {
    dev_csr_scatter(ei, row_ptr, pos, csr_src, bid - ENC1B - 2500);
  }
}

__global__ __launch_bounds__(256) void mega2(
    const float* PG, int nzG, const float* bg, const float* gg, const float* beg, u16* og,
    const float* PP, int nzP, const float* bp, const float* gp, const float* bep, u16* op,
    const u16* xl, const u16* xr, const float* att, const float* bias,
    const int* row_ptr, const int* csr_src, u16* out_b) {
  __shared__ float red[256];
  const int bid = blockIdx.x;
  if (bid < 2 * TH)
    dev_bn_part(bid, PG, nzG, bg, gg, beg, og, PP, nzP, bp, gp, bep, op, red);
  else
    dev_gat<HID>(xl, xr, att, bias, row_ptr, csr_src, out_b, bid - 2 * TH);
}

__global__ __launch_bounds__(256) void mega3(GP eg, GP ep, GP l, GP r) {
  __shared__ __align__(16) char smem[20480];
  const int bid = blockIdx.x;
  if (bid < 64) {
    const int z = bid >> 5, rem = bid & 31;
    dev_gemm_bt(z ? ep : eg, rem & 7, rem >> 3, smem);
  } else {
    const int sub = bid - 64;
    const GP& g = (sub >= 625) ? r : l;
    dev_gemm_bt(g, 0, sub % 625, smem);
  }
}

__global__ __launch_bounds__(256) void mega4(
    const float* Hg, const float* bg, const float* gg, const float* beg, u16* og,
    const float* Hp, const float* bp, const float* gp, const float* bep, u16* op,
    const u16* xl, const u16* xr, const float* att, const float* bias,
    const int* row_ptr, const int* csr_src, u16* out_b) {
  __shared__ float red[256];
  const int bid = blockIdx.x;
  if (bid < 2 * TH)
    dev_bn2(bid, Hg, bg, gg, beg, og, Hp, bp, gp, bep, op, red);
  else
    dev_gat<EMB>(xl, xr, att, bias, row_ptr, csr_src, out_b, bid - 2 * TH);
}

__global__ __launch_bounds__(256) void mega5(GP hg, GP hp, GP tg, GP tp) {
  __shared__ __align__(16) char smem[20480];
  const int bid = blockIdx.x;
  if (bid < 32) {
    const int z = bid >> 4, rem = bid & 15;
    dev_gemm_bt(z ? hp : hg, rem & 3, rem >> 2, smem);
  } else {
    const int sub = bid - 32;
    const GP& g = (sub >= 876) ? tp : tg;
    const int rem = sub % 876;
    dev_gemm_bt(g, rem & 1, rem >> 1, smem);
  }
}

__global__ __launch_bounds__(128) void mega6(
    const float* mld, const float* mlj, const float* mu_b, const float* ls_b,
    u16* thd, u16* thj, float* kl_out,
    const float* Lg, const float* Lp, float* bstats) {
  __shared__ float red[128];
  const int bid = blockIdx.x;
  if (bid < 2 * BATCH)
    dev_row_kl(bid % BATCH, bid / BATCH, mld, mlj, mu_b, ls_b, thd, thj, kl_out, red);
  else {
    const int sub = bid - 2 * BATCH;
    dev_col_stats(sub % NBMAX, sub / NBMAX, Lg, Lp, bstats);
  }
}

// ---------------------------- remaining kernels ----------------------------
__global__ __launch_bounds__(256) void scan_part(
    const int* __restrict__ deg, int* __restrict__ bsum) {
  const int base = blockIdx.x * SCAN_CHUNK + threadIdx.x * 4;
  int s = 0;
#pragma unroll
  for (int i = 0; i < 4; ++i) {
    const int idx = base + i;
    if (idx < N_NODES) s += deg[idx];
  }
  for (int o = 32; o > 0; o >>= 1) s += __shfl_down(s, o);
  __shared__ int ws[4];
  if ((threadIdx.x & 63) == 0) ws[threadIdx.x >> 6] = s;
  __syncthreads();
  if (threadIdx.x == 0) bsum[blockIdx.x] = ws[0] + ws[1] + ws[2] + ws[3];
}

__global__ __launch_bounds__(64) void scan_bsum(int* __restrict__ bsum) {
  if (threadIdx.x == 0) {
    int run = 0;
    for (int i = 0; i < SCAN_NB; ++i) { int v = bsum[i]; bsum[i] = run; run += v; }
  }
}

__global__ __launch_bounds__(256) void scan_final(
    const int* __restrict__ deg, const int* __restrict__ bsum,
    int* __restrict__ row_ptr) {
  const int t = threadIdx.x;
  const int base = blockIdx.x * SCAN_CHUNK + t * 4;
  int v[4], s = 0;
#pragma unroll
  for (int i = 0; i < 4; ++i) {
    const int idx = base + i;
    v[i] = (idx < N_NODES) ? deg[idx] : 0;
    s += v[i];
  }
  const int lane = t & 63, w = t >> 6;
  int x = s;
  for (int o = 1; o < 64; o <<= 1) {
    int y = __shfl_up(x, o);
    if (lane >= o) x += y;
  }
  __shared__ int wtot[4];
  if (lane == 63) wtot[w] = x;
  __syncthreads();
  int woff = 0;
  for (int i = 0; i < w; ++i) woff += wtot[i];
  int excl = bsum[blockIdx.x] + woff + x - s;
#pragma unroll
  for (int i = 0; i < 4; ++i) {
    const int idx = base + i;
    if (idx < N_NODES) { row_ptr[idx] = excl; excl += v[i]; }
  }
  if (blockIdx.x == 0 && t == 0) row_ptr[N_NODES] = E_TOTAL;
}

__global__ __launch_bounds__(64) void col_merge(
    const float* __restrict__ bstats, int nbG, int nbP,
    float* __restrict__ mstat, float* __restrict__ istat) {
  const bool sec = (blockIdx.y != 0);
  const int nb = sec ? nbP : nbG;
  const int c = blockIdx.x;
  const int l = threadIdx.x;
  const float* bs = bstats + ((size_t)blockIdx.y * NT + c) * NBMAX * 2;
  float m = -INFINITY, s = 0.f;
  for (int b = l; b < nb; b += 64) {
    const float mb = bs[b * 2];
    const float sb = bs[b * 2 + 1];
    const float nm = fmaxf(m, mb);
    s = s * __expf(m - nm) + sb * __expf(mb - nm);
    m = nm;
  }
#pragma unroll
  for (int o = 32; o > 0; o >>= 1) {
    const float mo = __shfl_xor(m, o);
    const float so = __shfl_xor(s, o);
    const float nm = fmaxf(m, mo);
    s = s * __expf(m - nm) + so * __expf(mo - nm);
    m = nm;
  }
  if (l == 0) {
    mstat[blockIdx.y * NT + c] = m;
    istat[blockIdx.y * NT + c] = 1.f / s;
  }
}

__global__ __launch_bounds__(256) void beta_norm(
    const float* __restrict__ Lg, const float* __restrict__ Lp,
    const float* __restrict__ mstat, const float* __restrict__ istat,
    u16* __restrict__ og, u16* __restrict__ op) {
  const float* L = blockIdx.y ? Lp : Lg;
  const int M = blockIdx.y ? NUM_PEAK : NUM_GENE;
  const float* mxg = mstat + blockIdx.y * NT;
  const float* ivg = istat + blockIdx.y * NT;
  u16* o = blockIdx.y ? op : og;
  __shared__ float mx[NT], inv[NT];
  for (int i = threadIdx.x; i < NT; i += 256) { mx[i] = mxg[i]; inv[i] = ivg[i]; }
  __syncthreads();
  const size_t total = (size_t)M * NTP;
  size_t i = (size_t)blockIdx.x * 256 + threadIdx.x;
  const size_t stride = (size_t)gridDim.x * 256;
  for (; i < total; i += stride) {
    const int c = (int)(i & (NTP - 1));
    u16 v = 0;
    if (c < NT) {
      const size_t r = i >> 7;
      v = f2bf(__expf(L[r * NT + c] - mx[c]) * inv[c]);
    }
    o[i] = v;
  }
}

__global__ __launch_bounds__(256) void recon_fused(
    const u16* __restrict__ thg, const u16* __restrict__ betag,
    const float* __restrict__ Xg, int Ng, int tiles_g,
    const u16* __restrict__ thp, const u16* __restrict__ betap,
    const float* __restrict__ Xp, int Np, float* __restrict__ partials) {
  __shared__ float pred[64][65];
  __shared__ float wsum[4];
  int ct = blockIdx.x;
  const u16* A; const u16* B; const float* X; int N;
  if (ct < tiles_g) { A = thg; B = betag; X = Xg; N = Ng; }
  else { ct -= tiles_g; A = thp; B = betap; X = Xp; N = Np; }
  const int bm = blockIdx.y * 64, bn = ct * 64;
  const int tid = threadIdx.x, w = tid >> 6, lane = tid & 63;
  const int wm = (w >> 1) * 32, wn = (w & 1) * 32;
  const int fr = lane & 15, ks = (lane >> 4) * 8;
  const u16* Ar0 = A + (size_t)(bm + wm + fr) * NTP;
  const u16* Ar1 = A + (size_t)(bm + wm + 16 + fr) * NTP;
  bf16x8 a0[4], a1[4];
#pragma unroll
  for (int kt = 0; kt < 4; ++kt) {
    a0[kt] = *(const bf16x8*)(Ar0 + kt * 32 + ks);
    a1[kt] = *(const bf16x8*)(Ar1 + kt * 32 + ks);
  }
  const int gn0 = min(bn + wn + fr, N - 1);
  const int gn1 = min(bn + wn + 16 + fr, N - 1);
  const u16* Br0 = B + (size_t)gn0 * NTP;
  const u16* Br1 = B + (size_t)gn1 * NTP;
  f32x4 acc[2][2] = {};
#pragma unroll
  for (int kt = 0; kt < 4; ++kt) {
    bf16x8 b0 = *(const bf16x8*)(Br0 + kt * 32 + ks);
    bf16x8 b1 = *(const bf16x8*)(Br1 + kt * 32 + ks);
    acc[0][0] = __builtin_amdgcn_mfma_f32_16x16x32_bf16(a0[kt], b0, acc[0][0], 0, 0, 0);
    acc[0][1] = __builtin_amdgcn_mfma_f32_16x16x32_bf16(a0[kt], b1, acc[0][1], 0, 0, 0);
    acc[1][0] = __builtin_amdgcn_mfma_f32_16x16x32_bf16(a1[kt], b0, acc[1][0], 0, 0, 0);
    acc[1][1] = __builtin_amdgcn_mfma_f32_16x16x32_bf16(a1[kt], b1, acc[1][1], 0, 0, 0);
  }
#pragma unroll
  for (int fi = 0; fi < 2; ++fi)
#pragma unroll
    for (int fj = 0; fj < 2; ++fj)
#pragma unroll
      for (int r = 0; r < 4; ++r)
        pred[wm + fi * 16 + (lane >> 4) * 4 + r][wn + fj * 16 + fr] = acc[fi][fj][r];
  __syncthreads();
  float local = 0.f;
  if (bn + 64 <= N) {
#pragma unroll
    for (int k = 0; k < 4; ++k) {
      const int j = k * 1024 + tid * 4;
      const int row = j >> 6, col = j & 63;
      const float4 xv = *(const float4*)(X + (size_t)(bm + row) * N + bn + col);
      local += xv.x * __logf(pred[row][col + 0] + 1e-6f);
      local += xv.y * __logf(pred[row][col + 1] + 1e-6f);
      local += xv.z * __logf(pred[row][col + 2] + 1e-6f);
      local += xv.w * __logf(pred[row][col + 3] + 1e-6f);
    }
  } else {
#pragma unroll
    for (int k = 0; k < 16; ++k) {
      const int idx = k * 256 + tid, row = idx >> 6, col = idx & 63;
      if (bn + col < N)
        local += X[(size_t)(bm + row) * N + bn + col] * __logf(pred[row][col] + 1e-6f);
    }
  }
  for (int o = 32; o > 0; o >>= 1) local += __shfl_down(local, o);
  if (lane == 0) wsum[w] = local;
  __syncthreads();
  if (tid == 0)
    partials[(size_t)blockIdx.y * gridDim.x + blockIdx.x] =
        wsum[0] + wsum[1] + wsum[2] + wsum[3];
}

__global__ __launch_bounds__(256) void final_recon(
    const float* __restrict__ partials, int n, float* __restrict__ out) {
  float s = 0.f;
  for (int i = threadIdx.x; i < n; i += 256) s += partials[i];
  __shared__ float red[256];
  red[threadIdx.x] = s; __syncthreads();
  for (int o = 128; o > 0; o >>= 1) {
    if (threadIdx.x < o) red[threadIdx.x] += red[threadIdx.x + o];
    __syncthreads();
  }
  if (threadIdx.x == 0) out[0] = -red[0] * (1.f / BATCH);
}

// ---------------------------------------------------------------------------
extern "C" void kernel_launch(void* const* d_in, const int* in_sizes, int n_in,
                              void* d_out, int out_size, void* d_ws, size_t ws_size,
                              hipStream_t stream) {
  const float* Gene  = (const float*)d_in[0];
  const float* GeneN = (const float*)d_in[1];
  const float* Peak  = (const float*)d_in[2];
  const float* PeakN = (const float*)d_in[3];
  const float* feat  = (const float*)d_in[4];
  const float* Wl1 = (const float*)d_in[5];  const float* bl1 = (const float*)d_in[6];
  const float* Wr1 = (const float*)d_in[7];  const float* br1 = (const float*)d_in[8];
  const float* att1 = (const float*)d_in[9]; const float* bias1 = (const float*)d_in[10];
  const float* Wl2 = (const float*)d_in[11]; const float* bl2 = (const float*)d_in[12];
  const float* Wr2 = (const float*)d_in[13]; const float* br2 = (const float*)d_in[14];
  const float* att2 = (const float*)d_in[15]; const float* bias2 = (const float*)d_in[16];
  const float* gW1 = (const float*)d_in[17]; const float* gb1 = (const float*)d_in[18];
  const float* gg1 = (const float*)d_in[19]; const float* gbe1 = (const float*)d_in[20];
  const float* gW2 = (const float*)d_in[21]; const float* gb2 = (const float*)d_in[22];
  const float* gg2 = (const float*)d_in[23]; const float* gbe2 = (const float*)d_in[24];
  const float* pW1 = (const float*)d_in[25]; const float* pb1 = (const float*)d_in[26];
  const float* pg1 = (const float*)d_in[27]; const float* pbe1 = (const float*)d_in[28];
  const float* pW2 = (const float*)d_in[29]; const float* pb2 = (const float*)d_in[30];
  const float* pg2 = (const float*)d_in[31]; const float* pbe2 = (const float*)d_in[32];
  const float* mu_W = (const float*)d_in[33]; const float* mu_b = (const float*)d_in[34];
  const float* ls_W = (const float*)d_in[35]; const float* ls_b = (const float*)d_in[36];
  const float* alphas_W = (const float*)d_in[37];
  const float* alphas_star_W = (const float*)d_in[38];
  const int* ei = (const int*)d_in[39];
  float* out = (float*)d_out;
  (void)in_sizes; (void)n_in; (void)ws_size;

  // ---- workspace layout (bytes) ----
  char* base = (char*)d_ws;
  size_t off = 0;
  auto A = [&](size_t bytes) { void* p = base + off; off += (bytes + 255) & ~(size_t)255; return p; };
  int* deg     = (int*)A((size_t)N_NODES * 4);
  int* row_ptr = (int*)A((size_t)(N_NODES + 1) * 4);
  int* bsum    = (int*)A((size_t)(SCAN_NB + 1) * 4);
  int* pos     = (int*)A((size_t)E_TOTAL * 4);
  int* csr_src = (int*)A((size_t)E_TOTAL * 4);
  float* CpartG = (float*)A((size_t)KSPG * TH * 256 * 4);
  float* CpartP = (float*)A((size_t)KSPP * TH * 256 * 4);
  float* h2g = (float*)A((size_t)BATCH * TH * 4);
  float* h2p = (float*)A((size_t)BATCH * TH * 4);
  u16* h1gb = (u16*)A((size_t)BATCH * TH * 2);
  u16* h2gb = (u16*)A((size_t)BATCH * TH * 2);
  u16* h1pb = (u16*)A((size_t)BATCH * TH * 2);
  u16* h2pb = (u16*)A((size_t)BATCH * TH * 2);
  float* ml_d = (float*)A((size_t)BATCH * NT2 * 4);
  float* ml_j = (float*)A((size_t)BATCH * NT2 * 4);
  u16* th_db = (u16*)A((size_t)BATCH * NTP * 2);
  u16* th_jb = (u16*)A((size_t)BATCH * NTP * 2);
  float* lgg = (float*)A((size_t)NUM_GENE * NT * 4);
  float* lgp = (float*)A((size_t)NUM_PEAK * NT * 4);
  u16* betagb = (u16*)A((size_t)NUM_GENE * NTP * 2);
  u16* betapb = (u16*)A((size_t)NUM_PEAK * NTP * 2);
  u16* featb = (u16*)A((size_t)N_NODES * EMB * 2);
  u16* gW2b = (u16*)A((size_t)TH * TH * 2);
  u16* pW2b = (u16*)A((size_t)TH * TH * 2);
  u16* mlWb = (u16*)A((size_t)NT2 * TH * 2);
  u16* Wl1b = (u16*)A((size_t)HID * EMB * 2);
  u16* Wr1b = (u16*)A((size_t)HID * EMB * 2);
  u16* Wl2b = (u16*)A((size_t)EMB * HID * 2);
  u16* Wr2b = (u16*)A((size_t)EMB * HID * 2);
  u16* aWb  = (u16*)A((size_t)NT * EMB * 2);
  u16* aSWb = (u16*)A((size_t)NT * EMB * 2);
  u16* agg1b = (u16*)A((size_t)N_NODES * HID * 2);
  u16* embb  = (u16*)A((size_t)N_NODES * EMB * 2);
  float* mstat = (float*)A(2 * NT * 4);
  float* istat = (float*)A(2 * NT * 4);
  float* bstats = (float*)A((size_t)2 * NT * NBMAX * 2 * 4);
  float* partials = (float*)A(4096 * 4);
  u16* xl1b = (u16*)A((size_t)N_NODES * HID * 2);
  u16* xr1b = (u16*)A((size_t)N_NODES * HID * 2);
  u16* xl2b = (u16*)A((size_t)N_NODES * EMB * 2);
  u16* xr2b = (u16*)A((size_t)N_NODES * EMB * 2);
  u16* GeneNb = (u16*)A((size_t)BATCH * KPG * 2);
  u16* PeakNb = (u16*)A((size_t)BATCH * KPP * 2);

  auto cdiv = [](int a, int b) { return (a + b - 1) / b; };
  auto Z = [&](void* p, size_t bytes) { hipMemsetAsync(p, 0, bytes, stream); };

  Z(d_out, (size_t)out_size * sizeof(float));
  Z(deg, (size_t)N_NODES * 4);

  // ---- megaA: deg_count(+pos) || cvt_pad || cvt_all ----
  int cvtallB;
  {
    CvtJobs J = {};
    int c = 0; u32 blocks = 0;
    auto add = [&](const float* s, u16* d, size_t n) {
      J.src[c] = s; J.dst[c] = d; J.n[c] = (u32)n; J.start[c] = blocks;
      blocks += (u32)((n + 2047) / 2048); ++c;
    };
    add(gW2, gW2b, (size_t)TH * TH);
    add(pW2, pW2b, (size_t)TH * TH);
    add(mu_W, mlWb, (size_t)NT * TH);
    add(ls_W, mlWb + (size_t)NT * TH, (size_t)NT * TH);
    add(feat, featb, (size_t)N_NODES * EMB);
    add(Wl1, Wl1b, (size_t)HID * EMB);
    add(Wr1, Wr1b, (size_t)HID * EMB);
    add(Wl2, Wl2b, (size_t)EMB * HID);
    add(Wr2, Wr2b, (size_t)EMB * HID);
    add(alphas_W, aWb, (size_t)NT * EMB);
    add(alphas_star_W, aSWb, (size_t)NT * EMB);
    J.count = c;
    cvtallB = (int)blocks;
    megaA<<<DEGB + PADGB + PADPB + cvtallB, 256, 0, stream>>>(
        ei, deg, pos, GeneN, GeneNb, PeakN, PeakNb, J);
  }

  // ---- scan chain (tiny) ----
  scan_part<<<SCAN_NB, 256, 0, stream>>>(deg, bsum);
  scan_bsum<<<1, 64, 0, stream>>>(bsum);
  scan_final<<<SCAN_NB, 256, 0, stream>>>(deg, bsum, row_ptr);

  // ---- mega1: enc1 + GAT L1 projections + atomic-free csr_scatter ----
  {
    GP l = {featb, Wl1b, nullptr, xl1b, bl1, N_NODES, HID, EMB};
    GP r = {featb, Wr1b, nullptr, xr1b, br1, N_NODES, HID, EMB};
    mega1<<<ENC1B + 2500 + DEGB, 256, 0, stream>>>(
        GeneNb, gW1, CpartG, PeakNb, pW1, CpartP, l, r,
        ei, row_ptr, pos, csr_src);
  }

  // ---- mega2: bn_part + gat<HID> ----
  mega2<<<2 * TH + N_NODES / 4, 256, 0, stream>>>(
      CpartG, KSPG, gb1, gg1, gbe1, h1gb,
      CpartP, KSPP, pb1, pg1, pbe1, h1pb,
      xl1b, xr1b, att1, bias1, row_ptr, csr_src, agg1b);

  // ---- mega3: enc L2 GEMM + GAT L2 projections ----
  {
    GP eg = {h1gb, gW2b, h2g, nullptr, nullptr, BATCH, TH, TH};
    GP ep = {h1pb, pW2b, h2p, nullptr, nullptr, BATCH, TH, TH};
    GP l  = {agg1b, Wl2b, nullptr, xl2b, bl2, N_NODES, EMB, HID};
    GP r  = {agg1b, Wr2b, nullptr, xr2b, br2, N_NODES, EMB, HID};
    mega3<<<64 + 1250, 256, 0, stream>>>(eg, ep, l, r);
  }

  // ---- mega4: bn2 + gat<EMB> ----
  mega4<<<2 * TH + N_NODES / 4, 256, 0, stream>>>(
      h2g, gb2, gg2, gbe2, h2gb,
      h2p, pb2, pg2, pbe2, h2pb,
      xl2b, xr2b, att2, bias2, row_ptr, csr_src, embb);

  // ---- mega5: heads GEMM + topic GEMM ----
  {
    GP hg = {h2gb, mlWb, ml_d, nullptr, nullptr, BATCH, NT2, TH};
    GP hp = {h2pb, mlWb, ml_j, nullptr, nullptr, BATCH, NT2, TH};
    GP tg = {embb + (size_t)NUM_PEAK * EMB, aWb, lgg, nullptr, nullptr, NUM_GENE, NT, EMB};
    GP tp = {embb, aSWb, lgp, nullptr, nullptr, NUM_PEAK, NT, EMB};
    mega5<<<32 + 2 * 2 * 438, 256, 0, stream>>>(hg, hp, tg, tp);
  }

  // ---- mega6: row_kl_theta + col_stats ----
  mega6<<<2 * BATCH + 2 * NBMAX, 128, 0, stream>>>(
      ml_d, ml_j, mu_b, ls_b, th_db, th_jb, out + 1, lgg, lgp, bstats);

  const int nbG = cdiv(NUM_GENE, CS_ROWS);   // 94
  const int nbP = cdiv(NUM_PEAK, CS_ROWS);   // 219
  col_merge<<<dim3(NT, 2), 64, 0, stream>>>(bstats, nbG, nbP, mstat, istat);
  beta_norm<<<dim3(1024, 2), 256, 0, stream>>>(lgg, lgp, mstat, istat, betagb, betapb);

  // ---- fused preds + recon ----
  const int tiles_g = cdiv(NUM_GENE, 64);
  const int tiles_p = cdiv(NUM_PEAK, 64);
  const int tiles = tiles_g + tiles_p;
  recon_fused<<<dim3(tiles, 4), 256, 0, stream>>>(
      th_db, betagb, Gene, NUM_GENE, tiles_g,
      th_jb, betapb, Peak, NUM_PEAK, partials);
  final_recon<<<1, 256, 0, stream>>>(partials, tiles * 4, out);
}